// Round 17
// baseline (131.095 us; speedup 1.0000x reference)
//
#include <hip/hip_runtime.h>
#include <stdint.h>
#include <stddef.h>

typedef int v4i __attribute__((ext_vector_type(4)));

#define GLOAD_LDS16(g, l) __builtin_amdgcn_global_load_lds( \
    (const __attribute__((address_space(1))) void*)(g),     \
    (__attribute__((address_space(3))) void*)(l), 16, 0, 0)

// ---------------------------------------------------------------------------
// Quantize rows of length 2048 for BOTH x and w in one dispatch:
// blocks [0, nx4) handle x rows (floor 1e-12); blocks [nx4, nx4+nw4) handle
// w rows (floor = clip(max,1e-8)/127 == max(max/127, 1e-8/127)).
// One wave per row, 4 rows per 256-thread block.
// scale = max(amax/127, floorv); q = clip(rint(v/scale), -128, 127)
// (IEEE div + rintf matches numpy round-half-even semantics.)
// ---------------------------------------------------------------------------
__device__ __forceinline__ int pack4(float4 f, float s) {
    int a = (int)rintf(f.x / s); a = a < -128 ? -128 : (a > 127 ? 127 : a);
    int b = (int)rintf(f.y / s); b = b < -128 ? -128 : (b > 127 ? 127 : b);
    int c = (int)rintf(f.z / s); c = c < -128 ? -128 : (c > 127 ? 127 : c);
    int d = (int)rintf(f.w / s); d = d < -128 ? -128 : (d > 127 ? 127 : d);
    return (a & 255) | ((b & 255) << 8) | ((c & 255) << 16) | ((d & 255) << 24);
}

__global__ __launch_bounds__(256) void quant_both_2048(
    const float* __restrict__ x, signed char* __restrict__ xq,
    float* __restrict__ xs,
    const float* __restrict__ w, signed char* __restrict__ wq,
    float* __restrict__ wsc, int nx4)
{
    const int lane = threadIdx.x & 63;
    const bool isx = ((int)blockIdx.x < nx4);
    const int rb   = isx ? blockIdx.x : (blockIdx.x - nx4);
    const int row  = rb * 4 + (threadIdx.x >> 6);
    const float* in = isx ? x : w;
    signed char* q  = isx ? xq : wq;
    float* scales   = isx ? xs : wsc;
    const float floorv = isx ? 1e-12f : (1e-8f / 127.0f);
    const float* rp = in + (size_t)row * 2048;

    float4 v[8];
#pragma unroll
    for (int j = 0; j < 2; ++j) {
        const float4* p = (const float4*)(rp + j * 1024 + lane * 16);
#pragma unroll
        for (int i = 0; i < 4; ++i) v[j * 4 + i] = p[i];
    }
    float am = 0.0f;
#pragma unroll
    for (int i = 0; i < 8; ++i) {
        am = fmaxf(am, fabsf(v[i].x));
        am = fmaxf(am, fabsf(v[i].y));
        am = fmaxf(am, fabsf(v[i].z));
        am = fmaxf(am, fabsf(v[i].w));
    }
#pragma unroll
    for (int off = 32; off; off >>= 1) am = fmaxf(am, __shfl_xor(am, off));
    const float s = fmaxf(am / 127.0f, floorv);

#pragma unroll
    for (int j = 0; j < 2; ++j) {
        int4 pk;
        pk.x = pack4(v[j * 4 + 0], s);
        pk.y = pack4(v[j * 4 + 1], s);
        pk.z = pack4(v[j * 4 + 2], s);
        pk.w = pack4(v[j * 4 + 3], s);
        *(int4*)(q + (size_t)row * 2048 + j * 1024 + lane * 16) = pk;
    }
    if (lane == 0) scales[row] = s;
}

// ---------------------------------------------------------------------------
// int8 GEMM — R9's PROVEN loose-ring sync skeleton at 128x128 tile so the
// ring-3 fits in 48 KB -> THREE blocks/CU (3 independent barrier domains,
// 12 waves/CU): the untested occupancy axis. Domain count was the only
// variable that ever moved MfmaUtil (1 dom: 19-27%, 2 dom: 28-32%).
// 128x128 tile, BK=64, 256 thr = 4 waves (2M x 2N), wave 64x64 via 4x4
// frags of mfma_i32_16x16x64_i8 (verified layouts, VGPR 64).
// Per tile t: {8 ds_read frags of buf t%3; ST4(t+2) -> (t+2)%3; 16 MFMA
//  (compiler lgkm waits); vmcnt(4)+lgkmcnt(0) counted [drains ST4(t+1),
//  leaves ST4(t+2) in flight — never 0 mid-loop]; raw s_barrier}.
// WAR-safe: lgkm(0) before the barrier => all reads of buf (t)%3 returned
// before any wave issues the ST4 overwrite of that buf ((t+3)%3) after it.
// Swizzle: LDS chunk c of row r holds global chunk c ^ ((r>>1)&3); frag
// read chunk ko ^ ((rl>>1)&3) — 2-way bank aliasing = free (0 conflicts
// in R9-R15; layout algebra re-verified after R16).
// ---------------------------------------------------------------------------
__global__ __launch_bounds__(256, 3) void gemm_i8_r3s(
    const signed char* __restrict__ xq, const signed char* __restrict__ wq,
    const float* __restrict__ xs, const float* __restrict__ ws,
    const float* __restrict__ bias, float* __restrict__ out, int K)
{
    __shared__ __align__(16) signed char lds[49152]; // 3 x (A 8K | B 8K)

    const int tid  = threadIdx.x;
    const int lane = tid & 63;
    const int wid  = tid >> 6;        // 0..3
    const int wm   = wid >> 1;        // 0..1
    const int wn   = wid & 1;         // 0..1

    const int nwg  = gridDim.x * gridDim.y;
    int orig = blockIdx.y * gridDim.x + blockIdx.x;
    int swz  = ((nwg & 7) == 0) ? ((orig & 7) * (nwg >> 3) + (orig >> 3)) : orig;
    const int brow = (swz / gridDim.x) * 128;
    const int bcol = (swz % gridDim.x) * 128;

    // staging: thread -> (row = 64h + (tid>>2), chunk = tid&3), swizzled src;
    // (tid>>3)&3 == (row>>1)&3 for both halves (64h contributes 0 mod 4).
    const int gch = (((tid & 3) ^ ((tid >> 3) & 3)) << 4);
    const signed char* gA = xq + (size_t)(brow + (tid >> 2)) * K;
    const signed char* gB = wq + (size_t)(bcol + (tid >> 2)) * K;

#define ST4(tt, bb) do {                                                                  \
    GLOAD_LDS16(gA + (size_t)(tt) * 64 + gch,                  lds + (bb) * 16384 + (tid << 4));         \
    GLOAD_LDS16(gA + (size_t)64 * K + (size_t)(tt) * 64 + gch, lds + (bb) * 16384 + 4096 + (tid << 4));  \
    GLOAD_LDS16(gB + (size_t)(tt) * 64 + gch,                  lds + (bb) * 16384 + 8192 + (tid << 4));  \
    GLOAD_LDS16(gB + (size_t)64 * K + (size_t)(tt) * 64 + gch, lds + (bb) * 16384 + 12288 + (tid << 4)); \
} while (0)

    const int rl   = lane & 15;
    const int ko   = lane >> 4;
    const int slot = ((ko ^ ((rl >> 1) & 3)) << 4);

#define FRAG_A(bb, r) (*(const v4i*)(lds + (bb) * 16384 + (r) * 64 + slot))
#define FRAG_B(bb, r) (*(const v4i*)(lds + (bb) * 16384 + 8192 + (r) * 64 + slot))

    v4i acc[4][4] = {};
    const int ar = wm * 64 + rl;
    const int br = wn * 64 + rl;

    // ---- prologue: stage tiles 0,1; tile 0 resident (counted); barrier
    ST4(0, 0);
    ST4(1, 1);
    asm volatile("s_waitcnt vmcnt(4)" ::: "memory");
    __builtin_amdgcn_s_barrier();

    const int NT = K >> 6;   // 32
    for (int t = 0; t < NT; ++t) {
        const int buf = t % 3;

        // reads first (critical path), then stage t+2 (2-window slack)
        v4i af[4], bf[4];
#pragma unroll
        for (int m = 0; m < 4; ++m) af[m] = FRAG_A(buf, ar + m * 16);
#pragma unroll
        for (int n = 0; n < 4; ++n) bf[n] = FRAG_B(buf, br + n * 16);

        if (t + 2 < NT) ST4(t + 2, (t + 2) % 3);

#pragma unroll
        for (int m = 0; m < 4; ++m)
#pragma unroll
            for (int n = 0; n < 4; ++n)
                acc[m][n] = __builtin_amdgcn_mfma_i32_16x16x64_i8(
                    af[m], bf[n], acc[m][n], 0, 0, 0);

        if (t + 2 < NT) {
            // ST4(t+1) drained (t+1 resident); ST4(t+2)'s 4 stay in flight
            asm volatile("s_waitcnt vmcnt(4) lgkmcnt(0)" ::: "memory");
            __builtin_amdgcn_s_barrier();
        } else if (t + 2 == NT) {
            asm volatile("s_waitcnt vmcnt(0) lgkmcnt(0)" ::: "memory");
            __builtin_amdgcn_s_barrier();
        }
        // t == NT-1: no further loads, fall through to epilogue
    }

    // ---- epilogue: C/D layout col = lane&15, row = (lane>>4)*4 + j
    const int rg = lane >> 4;
#pragma unroll
    for (int n = 0; n < 4; ++n) {
        const int col = bcol + wn * 64 + n * 16 + rl;
        const float wsc = ws[col];
        const float bv  = bias[col];
#pragma unroll
        for (int m = 0; m < 4; ++m) {
#pragma unroll
            for (int j = 0; j < 4; ++j) {
                const int row = brow + wm * 64 + m * 16 + rg * 4 + j;
                out[(size_t)row * 2048 + col] =
                    (float)acc[m][n][j] * xs[row] * wsc + bv;
            }
        }
    }
#undef ST4
#undef FRAG_A
#undef FRAG_B
}

// ---------------------------------------------------------------------------
extern "C" void kernel_launch(void* const* d_in, const int* in_sizes, int n_in,
                              void* d_out, int out_size, void* d_ws, size_t ws_size,
                              hipStream_t stream) {
    const float* x    = (const float*)d_in[0];   // [B,N,D] = [4,4096,2048]
    const float* w    = (const float*)d_in[1];   // [O,D]   = [2048,2048]
    const float* bias = (const float*)d_in[2];   // [O]
    float* out = (float*)d_out;

    const int D = 2048;
    const int O = in_sizes[2];                   // 2048
    const int M = in_sizes[0] / D;               // 16384

    char* wsb = (char*)d_ws;
    signed char* xq  = (signed char*)wsb;
    signed char* wqp = (signed char*)(wsb + (size_t)M * D);
    float* xs  = (float*)(wsb + (size_t)M * D + (size_t)O * D);
    float* wsc = (float*)(wsb + (size_t)M * D + (size_t)O * D + (size_t)M * 4);

    // one dispatch quantizes both x and w (identical per-row arithmetic)
    quant_both_2048<<<(M + O) / 4, 256, 0, stream>>>(x, xq, xs, w, wqp, wsc, M / 4);

    dim3 grid(O / 128, M / 128);   // (16, 128) = 2048 blocks, %8 == 0
    gemm_i8_r3s<<<grid, 256, 0, stream>>>(xq, wqp, xs, wsc, bias, out, D);
}